// Round 3
// baseline (981.350 us; speedup 1.0000x reference)
//
#include <hip/hip_runtime.h>
#include <math.h>

// Problem constants
#define kH  1024
#define kB  64
#define kS  256
#define kV  10000
#define kH3 3072

// ---------------- helpers ----------------
__device__ __forceinline__ float warp_sum(float v) {
#pragma unroll
  for (int off = 32; off > 0; off >>= 1) v += __shfl_down(v, off, 64);
  return v;  // valid on lane 0
}
__device__ __forceinline__ float warp_max_all(float v) {
#pragma unroll
  for (int off = 32; off > 0; off >>= 1) v = fmaxf(v, __shfl_xor(v, off, 64));
  return v;
}
__device__ __forceinline__ float warp_sum_all(float v) {
#pragma unroll
  for (int off = 32; off > 0; off >>= 1) v += __shfl_xor(v, off, 64);
  return v;
}
__device__ __forceinline__ float sigmoidf_(float x) { return 1.0f / (1.0f + __expf(-x)); }

// ---------------- GIp[r][t] = (emb[seq[t]] . W_ih[r]) + b_ih[r] ----------------
// TRANSPOSED output (r-major, t-minor) so k_gru blocks can preload their GI
// slice with coalesced row reads. One wave per 4 rows (x-row reused 4x:
// L2 traffic 786 MB -> 196 MB vs round 2). grid 192 x 256.
__global__ __launch_bounds__(256) void k_gi(const int* __restrict__ seq,
    const float* __restrict__ emb, const float* __restrict__ W_ih,
    const float* __restrict__ b_ih, float* __restrict__ GIp) {
  const int lane = threadIdx.x & 63;
  const int gw = blockIdx.x * 4 + (threadIdx.x >> 6);  // 0..767
  const int r0 = gw * 4;
  float wreg[4][16];
#pragma unroll
  for (int rr = 0; rr < 4; ++rr) {
    const float4* wp = (const float4*)(W_ih + (size_t)(r0 + rr) * kH) + lane * 4;
#pragma unroll
    for (int c = 0; c < 4; ++c) {
      const float4 f = wp[c];
      wreg[rr][c * 4 + 0] = f.x; wreg[rr][c * 4 + 1] = f.y;
      wreg[rr][c * 4 + 2] = f.z; wreg[rr][c * 4 + 3] = f.w;
    }
  }
  const float4 br = *(const float4*)(b_ih + r0);
  const float brr[4] = { br.x, br.y, br.z, br.w };
  for (int t = 0; t < kB; ++t) {
    const int tok = seq[t];
    float x[16];
    {
      const float4* xp = (const float4*)(emb + (size_t)tok * kH) + lane * 4;
#pragma unroll
      for (int c = 0; c < 4; ++c) {
        const float4 f = xp[c];
        x[c * 4 + 0] = f.x; x[c * 4 + 1] = f.y;
        x[c * 4 + 2] = f.z; x[c * 4 + 3] = f.w;
      }
    }
    float acc[4];
#pragma unroll
    for (int rr = 0; rr < 4; ++rr) {
      float a = 0.f;
#pragma unroll
      for (int u = 0; u < 16; ++u) a += wreg[rr][u] * x[u];
      acc[rr] = warp_sum(a);
    }
    if (lane == 0) {
#pragma unroll
      for (int rr = 0; rr < 4; ++rr)
        GIp[(size_t)(r0 + rr) * kB + t] = acc[rr] + brr[rr];
    }
  }
}

// ---------------- Persistent GRU scan, v3 ----------------
// grid 256 x 256 (1 block/CU, all resident). Wave g = bid*4+w owns h[g].
// Rows {g, H+g, 2H+g} of W_hh in registers (48 VGPR). GI slice for the
// block's 4 h-indices preloaded to LDS (768 floats). Scan loop has ZERO
// barriers and zero global loads except the tagged h polls:
// each thread directly polls its 16 slots hx[u]=h[u*64+lane] (coalesced
// 8B tagged u64, relaxed agent atomics), predicated pending-mask retry.
// h_old lives in lane0's register. Publish = one tagged atomic store.
__global__ __launch_bounds__(256) void k_gru(const float* __restrict__ h0,
    const float* __restrict__ W_hh, const float* __restrict__ b_hh,
    const float* __restrict__ GIp, float* __restrict__ rnn,
    unsigned long long* __restrict__ step) {
  __shared__ float gis[12 * kB];  // [gate*4+jj][t]
  const int tid = threadIdx.x, lane = tid & 63, w = tid >> 6;
  const int bid = blockIdx.x;
  const int j0 = bid * 4, j = j0 + w;

  for (int idx = tid; idx < 12 * kB; idx += 256) {
    const int row = idx >> 6, t = idx & 63;   // row = gate*4 + jj
    const int gate = row >> 2, jj = row & 3;
    gis[idx] = GIp[(size_t)(gate * kH + j0 + jj) * kB + t];
  }

  float wr[16], wz[16], wn[16];
  {
    const float* pr = W_hh + (size_t)j * kH + lane;
    const float* pz = W_hh + (size_t)(kH + j) * kH + lane;
    const float* pn = W_hh + (size_t)(2 * kH + j) * kH + lane;
#pragma unroll
    for (int u = 0; u < 16; ++u) {
      wr[u] = pr[u * 64]; wz[u] = pz[u * 64]; wn[u] = pn[u * 64];
    }
  }
  const float bhr = b_hh[j], bhz = b_hh[kH + j], bhn = b_hh[2 * kH + j];
  float cur = h0[j];  // h_old, maintained on lane 0
  __syncthreads();    // gis ready (only barrier in the kernel)

  for (int t = 0; t < kB; ++t) {
    float hx[16];
    if (t == 0) {
#pragma unroll
      for (int u = 0; u < 16; ++u) hx[u] = h0[u * 64 + lane];
    } else {
      const unsigned long long* sb = step + (size_t)(t - 1) * kH;
      const unsigned want = (unsigned)t;
      unsigned pend = 0xFFFFu;
      while (pend) {
#pragma unroll
        for (int u = 0; u < 16; ++u) {
          if (pend & (1u << u)) {
            const unsigned long long v = __hip_atomic_load(&sb[u * 64 + lane],
                __ATOMIC_RELAXED, __HIP_MEMORY_SCOPE_AGENT);
            if ((unsigned)(v >> 32) == want) {
              hx[u] = __uint_as_float((unsigned)v);
              pend &= ~(1u << u);
            }
          }
        }
      }
    }
    float ar = 0.f, az = 0.f, an = 0.f;
#pragma unroll
    for (int u = 0; u < 16; ++u) {
      ar += wr[u] * hx[u]; az += wz[u] * hx[u]; an += wn[u] * hx[u];
    }
    ar = warp_sum(ar); az = warp_sum(az); an = warp_sum(an);
    if (lane == 0) {
      const float gr = gis[(0 + w) * kB + t];
      const float gz = gis[(4 + w) * kB + t];
      const float gn = gis[(8 + w) * kB + t];
      const float r = sigmoidf_(gr + ar + bhr);
      const float z = sigmoidf_(gz + az + bhz);
      const float xn = gn + r * (an + bhn);
      const float e2 = __expf(2.f * xn);
      const float n = 1.f - 2.f / (e2 + 1.f);   // tanh, no inf/inf
      const float hn = (1.f - z) * n + z * cur;
      cur = hn;
      __hip_atomic_store(&step[(size_t)t * kH + j],
          (((unsigned long long)(t + 1)) << 32) | __float_as_uint(hn),
          __ATOMIC_RELAXED, __HIP_MEMORY_SCOPE_AGENT);
      rnn[(size_t)t * kH + j] = hn;
    }
  }
}

// ---------------- w2h stage A: coalesced partials ----------------
// w2h[k] = sum_h v_attn[h]*W_attn[h][H+k]. Block p does rows [16p,16p+16):
// per row the block reads 4 KB contiguous. grid 64 x 256.
__global__ __launch_bounds__(256) void k_w2hp(const float* __restrict__ W_attn,
    const float* __restrict__ v_attn, float* __restrict__ p2) {
  const int p = blockIdx.x, t = threadIdx.x;
  float ax = 0, ay = 0, az = 0, aw = 0;
#pragma unroll 4
  for (int hh = 0; hh < 16; ++hh) {
    const int h = p * 16 + hh;
    const float vh = v_attn[h];
    const float4 wq = *(const float4*)(W_attn + (size_t)h * 2048 + kH + 4 * t);
    ax += vh * wq.x; ay += vh * wq.y; az += vh * wq.z; aw += vh * wq.w;
  }
  *(float4*)(p2 + (size_t)p * kH + 4 * t) = make_float4(ax, ay, az, aw);
}

// ---------------- w2h stage B + hidden-output copy ----------------
// grid 4 x 256.
__global__ __launch_bounds__(256) void k_w2hr(const float* __restrict__ p2,
    const float* __restrict__ rnn, float* __restrict__ w2h,
    float* __restrict__ hid) {
  const int k = blockIdx.x * 256 + threadIdx.x;
  float a = 0.f;
#pragma unroll 8
  for (int p = 0; p < 64; ++p) a += p2[(size_t)p * kH + k];
  w2h[k] = a;
  hid[k] = rnn[63 * kH + k];
}

// ---------------- scores[b][s] = enc[s][b][:] . w2h ----------------
__global__ __launch_bounds__(256) void k_scores(const float* __restrict__ enc,
    const float* __restrict__ w2h, float* __restrict__ sc) {
  const int lane = threadIdx.x & 63;
  const int wg = blockIdx.x * 4 + (threadIdx.x >> 6);  // 0..16383
  const int b = wg & 63, s = wg >> 6;
  const float4* ep = (const float4*)(enc + ((size_t)s * kB + b) * kH) + lane * 4;
  const float4* wp = (const float4*)w2h + lane * 4;
  float acc = 0.f;
#pragma unroll
  for (int c = 0; c < 4; ++c) {
    const float4 e = ep[c], wq = wp[c];
    acc += e.x * wq.x + e.y * wq.y + e.z * wq.z + e.w * wq.w;
  }
  acc = warp_sum(acc);
  if (lane == 0) sc[b * kS + s] = acc;
}

// ---------------- softmax (fused) + context partials ----------------
// blockIdx = ch*64 + b. Each block redundantly computes the row softmax
// (cheap) then accumulates its 64-s chunk. ch==0 blocks write attn output.
__global__ __launch_bounds__(256) void k_context(const float* __restrict__ enc,
    const float* __restrict__ sc, float* __restrict__ attn,
    float* __restrict__ part) {
  __shared__ float sm[4], ss[4], ap[kS];
  const int b = blockIdx.x & 63, ch = blockIdx.x >> 6;
  const int t = threadIdx.x, lane = t & 63, w = t >> 6;
  const float x = sc[b * kS + t];
  float m = warp_max_all(x);
  if (lane == 0) sm[w] = m;
  __syncthreads();
  m = fmaxf(fmaxf(sm[0], sm[1]), fmaxf(sm[2], sm[3]));
  const float e = __expf(x - m);
  float s = warp_sum_all(e);
  if (lane == 0) ss[w] = s;
  __syncthreads();
  s = ss[0] + ss[1] + ss[2] + ss[3];
  const float p = e / s;
  ap[t] = p;
  if (ch == 0) attn[b * kS + t] = p;
  __syncthreads();
  const int h0_ = t * 4;
  float ax = 0, ay = 0, az = 0, aw = 0;
  const int s0 = ch * 64;
  for (int si = s0; si < s0 + 64; ++si) {
    const float a = ap[si];
    const float4 v = *(const float4*)(enc + ((size_t)si * kB + b) * kH + h0_);
    ax += a * v.x; ay += a * v.y; az += a * v.z; aw += a * v.w;
  }
  *(float4*)(part + ((size_t)ch * kB + b) * kH + h0_) =
      make_float4(ax, ay, az, aw);
}

// ---------------- coT[i][b] = tanh([rnn,ctx][b] . W_concat[i] + b_c[i]) ----------------
// One wave per (i, 8-b group): 8192 waves (8x round-2 parallelism).
// ctx is formed inline by summing the 4 PART chunks (k_ctxsum eliminated).
__global__ __launch_bounds__(256) void k_concat(const float* __restrict__ rnn,
    const float* __restrict__ part, const float* __restrict__ W_c,
    const float* __restrict__ b_c, float* __restrict__ coT) {
  const int lane = threadIdx.x & 63;
  const int gw = blockIdx.x * 4 + (threadIdx.x >> 6);  // 0..8191
  const int i = gw >> 3, c = gw & 7;
  float wreg[32];
  {
    const float4* wp = (const float4*)(W_c + (size_t)i * 2048) + lane * 8;
#pragma unroll
    for (int cc = 0; cc < 8; ++cc) {
      const float4 f = wp[cc];
      wreg[cc * 4 + 0] = f.x; wreg[cc * 4 + 1] = f.y;
      wreg[cc * 4 + 2] = f.z; wreg[cc * 4 + 3] = f.w;
    }
  }
  const float bc = b_c[i];
  const int jcol = lane * 32;
  for (int bb = 0; bb < 8; ++bb) {
    const int b = c * 8 + bb;
    float acc = 0.f;
    if (jcol < kH) {
      const float* xr = rnn + (size_t)b * kH + jcol;
#pragma unroll
      for (int cc = 0; cc < 8; ++cc) {
        const float4 xv = *(const float4*)(xr + cc * 4);
        acc += wreg[cc * 4 + 0] * xv.x + wreg[cc * 4 + 1] * xv.y +
               wreg[cc * 4 + 2] * xv.z + wreg[cc * 4 + 3] * xv.w;
      }
    } else {
      const int hc = jcol - kH;
#pragma unroll
      for (int cc = 0; cc < 8; ++cc) {
        float4 xs = make_float4(0, 0, 0, 0);
#pragma unroll
        for (int ch = 0; ch < 4; ++ch) {
          const float4 pv = *(const float4*)(part +
              ((size_t)ch * kB + b) * kH + hc + cc * 4);
          xs.x += pv.x; xs.y += pv.y; xs.z += pv.z; xs.w += pv.w;
        }
        acc += wreg[cc * 4 + 0] * xs.x + wreg[cc * 4 + 1] * xs.y +
               wreg[cc * 4 + 2] * xs.z + wreg[cc * 4 + 3] * xs.w;
      }
    }
    acc = warp_sum(acc);
    if (lane == 0) coT[(size_t)i * kB + b] = tanhf(acc + bc);
  }
}

// ---------------- output[b][v] = coT[:,b] . W_out[v] + b_out[v] ----------------
__global__ __launch_bounds__(256) void k_out(const float* __restrict__ coT,
    const float* __restrict__ W_out, const float* __restrict__ b_out,
    float* __restrict__ out) {
  const int lane = threadIdx.x & 63;
  int wg = blockIdx.x * 4 + (threadIdx.x >> 6);
  wg = __builtin_amdgcn_readfirstlane(wg);   // wave-uniform -> s_loads
  const int v0 = wg * 10;
  float acc[10];
#pragma unroll
  for (int i = 0; i < 10; ++i) acc[i] = 0.f;
  for (int h = 0; h < kH; h += 4) {
    const float x0 = coT[(h + 0) * kB + lane];
    const float x1 = coT[(h + 1) * kB + lane];
    const float x2 = coT[(h + 2) * kB + lane];
    const float x3 = coT[(h + 3) * kB + lane];
#pragma unroll
    for (int i = 0; i < 10; ++i) {
      const float4 wq = *(const float4*)(W_out + (size_t)(v0 + i) * kH + h);
      acc[i] += wq.x * x0 + wq.y * x1 + wq.z * x2 + wq.w * x3;
    }
  }
#pragma unroll
  for (int i = 0; i < 10; ++i)
    out[(size_t)lane * kV + v0 + i] = acc[i] + b_out[v0 + i];
}

// ---------------- launcher ----------------
extern "C" void kernel_launch(void* const* d_in, const int* in_sizes, int n_in,
                              void* d_out, int out_size, void* d_ws,
                              size_t ws_size, hipStream_t stream) {
  const int*   seq    = (const int*)  d_in[0];
  const float* h0     = (const float*)d_in[1];
  const float* enc    = (const float*)d_in[2];
  const float* emb    = (const float*)d_in[3];
  const float* W_ih   = (const float*)d_in[4];
  const float* W_hh   = (const float*)d_in[5];
  const float* b_ih   = (const float*)d_in[6];
  const float* b_hh   = (const float*)d_in[7];
  const float* W_attn = (const float*)d_in[8];
  // d_in[9] = b_attn: drops out of softmax (shift invariance)
  const float* v_attn = (const float*)d_in[10];
  const float* W_conc = (const float*)d_in[11];
  const float* b_conc = (const float*)d_in[12];
  const float* W_outp = (const float*)d_in[13];
  const float* b_outp = (const float*)d_in[14];

  float* out      = (float*)d_out;           // (B,V) = 640000
  float* out_hid  = out + 640000;            // (1,1,H) = 1024
  float* out_attn = out + 641024;            // (B,1,S) = 16384

  float* ws = (float*)d_ws;
  float* GIp  = ws;                      // 3072*64 = 196608
  float* RNN  = ws + 196608;             // 64*1024 =  65536 -> 262144
  unsigned long long* STEP =
      (unsigned long long*)(ws + 262144);  // 64*1024 u64 = 131072 f -> 393216
  float* P2   = ws + 393216;             // 64*1024 =  65536 -> 458752
  float* W2H  = ws + 458752;             // 1024            -> 459776
  float* SC   = ws + 459776;             // 64*256  =  16384 -> 476160
  float* PART = ws + 476160;             // 4*64*1024=262144 -> 738304
  float* COT  = ws + 738304;             // 1024*64 =  65536 -> 803840 floats

  k_gi<<<192, 256, 0, stream>>>(seq, emb, W_ih, b_ih, GIp);
  k_gru<<<256, 256, 0, stream>>>(h0, W_hh, b_hh, GIp, RNN, STEP);
  k_w2hp<<<64, 256, 0, stream>>>(W_attn, v_attn, P2);
  k_w2hr<<<4, 256, 0, stream>>>(P2, RNN, W2H, out_hid);
  k_scores<<<4096, 256, 0, stream>>>(enc, W2H, SC);
  k_context<<<256, 256, 0, stream>>>(enc, SC, out_attn, PART);
  k_concat<<<2048, 256, 0, stream>>>(RNN, PART, W_conc, b_conc, COT);
  k_out<<<250, 256, 0, stream>>>(COT, W_outp, b_outp, out);
}

// Round 4
// 869.925 us; speedup vs baseline: 1.1281x; 1.1281x over previous
//
#include <hip/hip_runtime.h>
#include <math.h>

// Problem constants
#define kH  1024
#define kB  64
#define kS  256
#define kV  10000
#define kH3 3072

// ---------------- helpers ----------------
__device__ __forceinline__ float warp_sum(float v) {
#pragma unroll
  for (int off = 32; off > 0; off >>= 1) v += __shfl_down(v, off, 64);
  return v;  // valid on lane 0
}
__device__ __forceinline__ float warp_max_all(float v) {
#pragma unroll
  for (int off = 32; off > 0; off >>= 1) v = fmaxf(v, __shfl_xor(v, off, 64));
  return v;
}
__device__ __forceinline__ float warp_sum_all(float v) {
#pragma unroll
  for (int off = 32; off > 0; off >>= 1) v += __shfl_xor(v, off, 64);
  return v;
}
__device__ __forceinline__ float sigmoidf_(float x) { return 1.0f / (1.0f + __expf(-x)); }

// ---------------- GIp[r][t] = (emb[seq[t]] . W_ih[r]) + b_ih[r] ----------------
// One wave per row (3072 waves = 3 waves/SIMD). Transposed write (r-major,
// t-minor) so k_gru blocks preload their GI slice coalesced. grid 768 x 256.
__global__ __launch_bounds__(256) void k_gi(const int* __restrict__ seq,
    const float* __restrict__ emb, const float* __restrict__ W_ih,
    const float* __restrict__ b_ih, float* __restrict__ GIp) {
  const int lane = threadIdx.x & 63;
  const int r = blockIdx.x * 4 + (threadIdx.x >> 6);
  const float4* wp = (const float4*)(W_ih + (size_t)r * kH) + lane * 4;
  const float4 w0 = wp[0], w1 = wp[1], w2 = wp[2], w3 = wp[3];
  const float br = b_ih[r];
  for (int t = 0; t < kB; ++t) {
    const int tok = seq[t];
    const float4* xp = (const float4*)(emb + (size_t)tok * kH) + lane * 4;
    const float4 x0 = xp[0], x1 = xp[1], x2 = xp[2], x3 = xp[3];
    float acc = w0.x*x0.x + w0.y*x0.y + w0.z*x0.z + w0.w*x0.w;
    acc += w1.x*x1.x + w1.y*x1.y + w1.z*x1.z + w1.w*x1.w;
    acc += w2.x*x2.x + w2.y*x2.y + w2.z*x2.z + w2.w*x2.w;
    acc += w3.x*x3.x + w3.y*x3.y + w3.z*x3.z + w3.w*x3.w;
    acc = warp_sum(acc);
    if (lane == 0) GIp[(size_t)r * kB + t] = acc + br;
  }
}

// ---------------- Persistent GRU scan, v4 ----------------
// 64 blocks x 1024 threads. Block owns h[16b..16b+15]; wave w owns h[16b+w]
// (rows {j, H+j, 2H+j} of W_hh in 48 VGPRs). Handshake (lesson from r2/r3):
// each THREAD polls exactly ONE tagged u64 slot (relaxed agent atomic, with
// s_sleep backoff -> only 64 reader-streams per cache line), stages into a
// DOUBLE-BUFFERED LDS h vector -> one barrier per step. GI slice pre-staged
// in LDS so the lane-0 tail has zero global loads. h_old kept in register.
// Publish = one tagged relaxed agent atomic store per wave.
__global__ __launch_bounds__(1024) void k_gru(const float* __restrict__ h0,
    const float* __restrict__ W_hh, const float* __restrict__ b_hh,
    const float* __restrict__ GIp, float* __restrict__ rnn,
    unsigned long long* __restrict__ step) {
  __shared__ float gis[3 * 16 * kB];  // [gate][jj][t] = 12 KB
  __shared__ float hs[2][kH];         // double-buffered h broadcast, 8 KB
  const int tid = threadIdx.x, lane = tid & 63, w = tid >> 6;  // w 0..15
  const int bid = blockIdx.x;
  const int j0 = bid * 16, j = j0 + w;

  // GI slice: rows {gate*kH + j0+jj} for jj 0..15, all 64 t.
  for (int idx = tid; idx < 3 * 16 * kB; idx += 1024) {
    const int gate = idx >> 10, rem = idx & 1023;  // rem = jj*64 + t
    gis[idx] = GIp[(size_t)(gate * kH + j0) * kB + rem];
  }

  float wr[16], wz[16], wn[16];
  {
    const float* pr = W_hh + (size_t)j * kH + lane;
    const float* pz = W_hh + (size_t)(kH + j) * kH + lane;
    const float* pn = W_hh + (size_t)(2 * kH + j) * kH + lane;
#pragma unroll
    for (int u = 0; u < 16; ++u) {
      wr[u] = pr[u * 64]; wz[u] = pz[u * 64]; wn[u] = pn[u * 64];
    }
  }
  const float bhr = b_hh[j], bhz = b_hh[kH + j], bhn = b_hh[2 * kH + j];
  float cur = h0[j];   // h_old (used on lane 0)
  __syncthreads();     // gis ready

  for (int t = 0; t < kB; ++t) {
    float hx[16];
    if (t == 0) {
#pragma unroll
      for (int u = 0; u < 16; ++u) hx[u] = h0[u * 64 + lane];
    } else {
      // poll MY slot of step t-1 (tag == t)
      const unsigned long long* sb = step + (size_t)(t - 1) * kH;
      const unsigned want = (unsigned)t;
      unsigned long long v;
      while (true) {
        v = __hip_atomic_load(&sb[tid], __ATOMIC_RELAXED,
                              __HIP_MEMORY_SCOPE_AGENT);
        if ((unsigned)(v >> 32) == want) break;
        __builtin_amdgcn_s_sleep(1);
      }
      const int p = t & 1;
      hs[p][tid] = __uint_as_float((unsigned)v);
      __syncthreads();  // staging complete (only barrier in the step)
#pragma unroll
      for (int u = 0; u < 16; ++u) hx[u] = hs[p][u * 64 + lane];
    }

    float ar = 0.f, az = 0.f, an = 0.f;
#pragma unroll
    for (int u = 0; u < 16; ++u) {
      ar += wr[u] * hx[u]; az += wz[u] * hx[u]; an += wn[u] * hx[u];
    }
    ar = warp_sum(ar); az = warp_sum(az); an = warp_sum(an);

    if (lane == 0) {
      const float gr = gis[0 * 1024 + w * kB + t];
      const float gz = gis[1 * 1024 + w * kB + t];
      const float gn = gis[2 * 1024 + w * kB + t];
      const float r = sigmoidf_(gr + ar + bhr);
      const float z = sigmoidf_(gz + az + bhz);
      const float xn = gn + r * (an + bhn);
      const float e2 = __expf(2.f * xn);
      const float n = 1.f - 2.f / (e2 + 1.f);   // tanh
      const float hn = (1.f - z) * n + z * cur;
      cur = hn;
      __hip_atomic_store(&step[(size_t)t * kH + j],
          (((unsigned long long)(t + 1)) << 32) | __float_as_uint(hn),
          __ATOMIC_RELAXED, __HIP_MEMORY_SCOPE_AGENT);
      rnn[(size_t)t * kH + j] = hn;
    }
  }
}

// ---------------- w2h stage A: coalesced partials ----------------
// w2h[k] = sum_h v_attn[h]*W_attn[h][H+k]. grid 64 x 256.
__global__ __launch_bounds__(256) void k_w2hp(const float* __restrict__ W_attn,
    const float* __restrict__ v_attn, float* __restrict__ p2) {
  const int p = blockIdx.x, t = threadIdx.x;
  float ax = 0, ay = 0, az = 0, aw = 0;
#pragma unroll 4
  for (int hh = 0; hh < 16; ++hh) {
    const int h = p * 16 + hh;
    const float vh = v_attn[h];
    const float4 wq = *(const float4*)(W_attn + (size_t)h * 2048 + kH + 4 * t);
    ax += vh * wq.x; ay += vh * wq.y; az += vh * wq.z; aw += vh * wq.w;
  }
  *(float4*)(p2 + (size_t)p * kH + 4 * t) = make_float4(ax, ay, az, aw);
}

// ---------------- w2h stage B + hidden-output copy ---------------- grid 4x256
__global__ __launch_bounds__(256) void k_w2hr(const float* __restrict__ p2,
    const float* __restrict__ rnn, float* __restrict__ w2h,
    float* __restrict__ hid) {
  const int k = blockIdx.x * 256 + threadIdx.x;
  float a = 0.f;
#pragma unroll 8
  for (int p = 0; p < 64; ++p) a += p2[(size_t)p * kH + k];
  w2h[k] = a;
  hid[k] = rnn[63 * kH + k];
}

// ---------------- scores[b][s] = enc[s][b][:] . w2h ----------------
__global__ __launch_bounds__(256) void k_scores(const float* __restrict__ enc,
    const float* __restrict__ w2h, float* __restrict__ sc) {
  const int lane = threadIdx.x & 63;
  const int wg = blockIdx.x * 4 + (threadIdx.x >> 6);  // 0..16383
  const int b = wg & 63, s = wg >> 6;
  const float4* ep = (const float4*)(enc + ((size_t)s * kB + b) * kH) + lane * 4;
  const float4* wp = (const float4*)w2h + lane * 4;
  float acc = 0.f;
#pragma unroll
  for (int c = 0; c < 4; ++c) {
    const float4 e = ep[c], wq = wp[c];
    acc += e.x * wq.x + e.y * wq.y + e.z * wq.z + e.w * wq.w;
  }
  acc = warp_sum(acc);
  if (lane == 0) sc[b * kS + s] = acc;
}

// ---------------- softmax (fused) + context partials ----------------
// blockIdx = ch*64 + b; redundant row softmax then 64-s chunk accumulation.
__global__ __launch_bounds__(256) void k_context(const float* __restrict__ enc,
    const float* __restrict__ sc, float* __restrict__ attn,
    float* __restrict__ part) {
  __shared__ float sm[4], ss[4], ap[kS];
  const int b = blockIdx.x & 63, ch = blockIdx.x >> 6;
  const int t = threadIdx.x, lane = t & 63, w = t >> 6;
  const float x = sc[b * kS + t];
  float m = warp_max_all(x);
  if (lane == 0) sm[w] = m;
  __syncthreads();
  m = fmaxf(fmaxf(sm[0], sm[1]), fmaxf(sm[2], sm[3]));
  const float e = __expf(x - m);
  float s = warp_sum_all(e);
  if (lane == 0) ss[w] = s;
  __syncthreads();
  s = ss[0] + ss[1] + ss[2] + ss[3];
  const float p = e / s;
  ap[t] = p;
  if (ch == 0) attn[b * kS + t] = p;
  __syncthreads();
  const int h0_ = t * 4;
  float ax = 0, ay = 0, az = 0, aw = 0;
  const int s0 = ch * 64;
  for (int si = s0; si < s0 + 64; ++si) {
    const float a = ap[si];
    const float4 v = *(const float4*)(enc + ((size_t)si * kB + b) * kH + h0_);
    ax += a * v.x; ay += a * v.y; az += a * v.z; aw += a * v.w;
  }
  *(float4*)(part + ((size_t)ch * kB + b) * kH + h0_) =
      make_float4(ax, ay, az, aw);
}

// ---------------- coT[i][b] = tanh([rnn,ctx][b] . W_concat[i] + b_c[i]) ----------------
// One wave per (i, 8-b group); ctx formed inline from the 4 PART chunks.
__global__ __launch_bounds__(256) void k_concat(const float* __restrict__ rnn,
    const float* __restrict__ part, const float* __restrict__ W_c,
    const float* __restrict__ b_c, float* __restrict__ coT) {
  const int lane = threadIdx.x & 63;
  const int gw = blockIdx.x * 4 + (threadIdx.x >> 6);  // 0..8191
  const int i = gw >> 3, c = gw & 7;
  float wreg[32];
  {
    const float4* wp = (const float4*)(W_c + (size_t)i * 2048) + lane * 8;
#pragma unroll
    for (int cc = 0; cc < 8; ++cc) {
      const float4 f = wp[cc];
      wreg[cc * 4 + 0] = f.x; wreg[cc * 4 + 1] = f.y;
      wreg[cc * 4 + 2] = f.z; wreg[cc * 4 + 3] = f.w;
    }
  }
  const float bc = b_c[i];
  const int jcol = lane * 32;
  for (int bb = 0; bb < 8; ++bb) {
    const int b = c * 8 + bb;
    float acc = 0.f;
    if (jcol < kH) {
      const float* xr = rnn + (size_t)b * kH + jcol;
#pragma unroll
      for (int cc = 0; cc < 8; ++cc) {
        const float4 xv = *(const float4*)(xr + cc * 4);
        acc += wreg[cc * 4 + 0] * xv.x + wreg[cc * 4 + 1] * xv.y +
               wreg[cc * 4 + 2] * xv.z + wreg[cc * 4 + 3] * xv.w;
      }
    } else {
      const int hc = jcol - kH;
#pragma unroll
      for (int cc = 0; cc < 8; ++cc) {
        float4 xs = make_float4(0, 0, 0, 0);
#pragma unroll
        for (int ch = 0; ch < 4; ++ch) {
          const float4 pv = *(const float4*)(part +
              ((size_t)ch * kB + b) * kH + hc + cc * 4);
          xs.x += pv.x; xs.y += pv.y; xs.z += pv.z; xs.w += pv.w;
        }
        acc += wreg[cc * 4 + 0] * xs.x + wreg[cc * 4 + 1] * xs.y +
               wreg[cc * 4 + 2] * xs.z + wreg[cc * 4 + 3] * xs.w;
      }
    }
    acc = warp_sum(acc);
    if (lane == 0) coT[(size_t)i * kB + b] = tanhf(acc + bc);
  }
}

// ---------------- out[b][v] = coT[:,b] . W_out[v] + b_out[v] ----------------
// v4: 313 blocks x 256 threads. lane = b (coalesced coT b32 loads), the
// wave's 64 lanes share one v-group (vg wave-uniform via readfirstlane) so
// W_out row reads are wave-uniform (scalar-load friendly, one fetch/line).
// 8 v-rows per thread: 8 FMA per coT load. Total 655M MAC -> compute-bound
// ~10 us instead of latency-bound ~100 us (r3: 1 wave/CU serial streaming).
__global__ __launch_bounds__(256) void k_out(const float* __restrict__ coT,
    const float* __restrict__ W_out, const float* __restrict__ b_out,
    float* __restrict__ out) {
  const int b  = threadIdx.x & 63;
  const int vg = __builtin_amdgcn_readfirstlane(threadIdx.x >> 6);  // 0..3
  const int vb = blockIdx.x * 32 + vg * 8;
  const float* rowp[8];
#pragma unroll
  for (int q = 0; q < 8; ++q) {
    int vr = vb + q; if (vr > kV - 1) vr = kV - 1;  // clamp (blocks past 10000)
    rowp[q] = W_out + (size_t)vr * kH;
  }
  float acc[8];
#pragma unroll
  for (int q = 0; q < 8; ++q) acc[q] = 0.f;
  for (int k0 = 0; k0 < kH; k0 += 4) {
    const float c0 = coT[(k0 + 0) * kB + b];
    const float c1 = coT[(k0 + 1) * kB + b];
    const float c2 = coT[(k0 + 2) * kB + b];
    const float c3 = coT[(k0 + 3) * kB + b];
#pragma unroll
    for (int q = 0; q < 8; ++q) {
      const float4 wq = *(const float4*)(rowp[q] + k0);
      acc[q] += wq.x * c0 + wq.y * c1 + wq.z * c2 + wq.w * c3;
    }
  }
#pragma unroll
  for (int q = 0; q < 8; ++q) {
    const int v = vb + q;
    if (v < kV) out[(size_t)b * kV + v] = acc[q] + b_out[v];
  }
}

// ---------------- launcher ----------------
extern "C" void kernel_launch(void* const* d_in, const int* in_sizes, int n_in,
                              void* d_out, int out_size, void* d_ws,
                              size_t ws_size, hipStream_t stream) {
  const int*   seq    = (const int*)  d_in[0];
  const float* h0     = (const float*)d_in[1];
  const float* enc    = (const float*)d_in[2];
  const float* emb    = (const float*)d_in[3];
  const float* W_ih   = (const float*)d_in[4];
  const float* W_hh   = (const float*)d_in[5];
  const float* b_ih   = (const float*)d_in[6];
  const float* b_hh   = (const float*)d_in[7];
  const float* W_attn = (const float*)d_in[8];
  // d_in[9] = b_attn: drops out of softmax (shift invariance)
  const float* v_attn = (const float*)d_in[10];
  const float* W_conc = (const float*)d_in[11];
  const float* b_conc = (const float*)d_in[12];
  const float* W_outp = (const float*)d_in[13];
  const float* b_outp = (const float*)d_in[14];

  float* out      = (float*)d_out;           // (B,V) = 640000
  float* out_hid  = out + 640000;            // (1,1,H) = 1024
  float* out_attn = out + 641024;            // (B,1,S) = 16384

  float* ws = (float*)d_ws;
  float* GIp  = ws;                      // 3072*64 = 196608
  float* RNN  = ws + 196608;             // 64*1024 =  65536 -> 262144
  unsigned long long* STEP =
      (unsigned long long*)(ws + 262144);  // 64*1024 u64 = 131072 f -> 393216
  float* P2   = ws + 393216;             // 64*1024 =  65536 -> 458752
  float* W2H  = ws + 458752;             // 1024            -> 459776
  float* SC   = ws + 459776;             // 64*256  =  16384 -> 476160
  float* PART = ws + 476160;             // 4*64*1024=262144 -> 738304
  float* COT  = ws + 738304;             // 1024*64 =  65536 -> 803840 floats

  k_gi<<<768, 256, 0, stream>>>(seq, emb, W_ih, b_ih, GIp);
  k_gru<<<64, 1024, 0, stream>>>(h0, W_hh, b_hh, GIp, RNN, STEP);
  k_w2hp<<<64, 256, 0, stream>>>(W_attn, v_attn, P2);
  k_w2hr<<<4, 256, 0, stream>>>(P2, RNN, W2H, out_hid);
  k_scores<<<4096, 256, 0, stream>>>(enc, W2H, SC);
  k_context<<<256, 256, 0, stream>>>(enc, SC, out_attn, PART);
  k_concat<<<2048, 256, 0, stream>>>(RNN, PART, W_conc, b_conc, COT);
  k_out<<<313, 256, 0, stream>>>(COT, W_outp, b_outp, out);
}

// Round 5
// 796.248 us; speedup vs baseline: 1.2325x; 1.0925x over previous
//
#include <hip/hip_runtime.h>
#include <math.h>

// Problem constants
#define kH  1024
#define kB  64
#define kS  256
#define kV  10000
#define kH3 3072

// ---------------- helpers ----------------
__device__ __forceinline__ float warp_sum(float v) {
#pragma unroll
  for (int off = 32; off > 0; off >>= 1) v += __shfl_down(v, off, 64);
  return v;  // valid on lane 0
}
__device__ __forceinline__ float warp_max_all(float v) {
#pragma unroll
  for (int off = 32; off > 0; off >>= 1) v = fmaxf(v, __shfl_xor(v, off, 64));
  return v;
}
__device__ __forceinline__ float warp_sum_all(float v) {
#pragma unroll
  for (int off = 32; off > 0; off >>= 1) v += __shfl_xor(v, off, 64);
  return v;
}
__device__ __forceinline__ float sigmoidf_(float x) { return 1.0f / (1.0f + __expf(-x)); }

// ---------------- GIp[r][t] = (emb[seq[t]] . W_ih[r]) + b_ih[r] ----------------
// One wave per row (3072 waves). Transposed write (r-major, t-minor) so k_gru
// blocks preload their GI slice coalesced. grid 768 x 256.
__global__ __launch_bounds__(256) void k_gi(const int* __restrict__ seq,
    const float* __restrict__ emb, const float* __restrict__ W_ih,
    const float* __restrict__ b_ih, float* __restrict__ GIp) {
  const int lane = threadIdx.x & 63;
  const int r = blockIdx.x * 4 + (threadIdx.x >> 6);
  const float4* wp = (const float4*)(W_ih + (size_t)r * kH) + lane * 4;
  const float4 w0 = wp[0], w1 = wp[1], w2 = wp[2], w3 = wp[3];
  const float br = b_ih[r];
  for (int t = 0; t < kB; ++t) {
    const int tok = seq[t];
    const float4* xp = (const float4*)(emb + (size_t)tok * kH) + lane * 4;
    const float4 x0 = xp[0], x1 = xp[1], x2 = xp[2], x3 = xp[3];
    float acc = w0.x*x0.x + w0.y*x0.y + w0.z*x0.z + w0.w*x0.w;
    acc += w1.x*x1.x + w1.y*x1.y + w1.z*x1.z + w1.w*x1.w;
    acc += w2.x*x2.x + w2.y*x2.y + w2.z*x2.z + w2.w*x2.w;
    acc += w3.x*x3.x + w3.y*x3.y + w3.z*x3.z + w3.w*x3.w;
    acc = warp_sum(acc);
    if (lane == 0) GIp[(size_t)r * kB + t] = acc + br;
  }
}

// ---------------- Persistent GRU scan, v5 ----------------
// 64 blocks x 1024 threads. Block owns h[16b..16b+15]; wave w owns h[16b+w].
// r4 lesson (FETCH=198 MB/step): TCC does NOT coalesce atomic loads across
// lanes -> every 8B poll is a 64B MALL transaction; 65536 spinning pollers
// bandwidth-bound the coherence point. v5 separates DETECTION from FETCH:
//  - producers: tagged u64 value slots; after the end-of-step __syncthreads
//    (drains vmcnt -> value stores retired at coherence point), tid 0 stores
//    one per-block flag flg[t][bid] = t+1.
//  - consumers: ONLY wave 0 polls -- lane b polls flg[t-1][b] (64 lines
//    total, __all ballot, s_sleep backoff). ~1-2 MB/step instead of 198.
//  - after detect: barrier, each thread fetches its slot ONCE (tag-verified;
//    near-never spin fallback keeps correctness independent of store->flag
//    ordering), stages LDS, computes.
__global__ __launch_bounds__(1024) void k_gru(const float* __restrict__ h0,
    const float* __restrict__ W_hh, const float* __restrict__ b_hh,
    const float* __restrict__ GIp, float* __restrict__ rnn,
    unsigned long long* __restrict__ step, unsigned* __restrict__ flg) {
  __shared__ float gis[3 * 16 * kB];  // 12 KB
  __shared__ float hs[kH];            // 4 KB
  const int tid = threadIdx.x, lane = tid & 63, w = tid >> 6;  // w 0..15
  const int bid = blockIdx.x;
  const int j0 = bid * 16, j = j0 + w;

  for (int idx = tid; idx < 3 * 16 * kB; idx += 1024) {
    const int gate = idx >> 10, rem = idx & 1023;  // rem = jj*64 + t
    gis[idx] = GIp[(size_t)(gate * kH + j0) * kB + rem];
  }

  float wr[16], wz[16], wn[16];
  {
    const float* pr = W_hh + (size_t)j * kH + lane;
    const float* pz = W_hh + (size_t)(kH + j) * kH + lane;
    const float* pn = W_hh + (size_t)(2 * kH + j) * kH + lane;
#pragma unroll
    for (int u = 0; u < 16; ++u) {
      wr[u] = pr[u * 64]; wz[u] = pz[u * 64]; wn[u] = pn[u * 64];
    }
  }
  const float bhr = b_hh[j], bhz = b_hh[kH + j], bhn = b_hh[2 * kH + j];
  float cur = h0[j];   // h_old (used on lane 0)
  __syncthreads();     // gis ready

  for (int t = 0; t < kB; ++t) {
    float hx[16];
    if (t == 0) {
#pragma unroll
      for (int u = 0; u < 16; ++u) hx[u] = h0[u * 64 + lane];
    } else {
      const unsigned want = (unsigned)t;  // step t-1 published tag/flag t
      if (w == 0) {
        const unsigned* fb = flg + (size_t)(t - 1) * kB;
        while (true) {
          const unsigned f = __hip_atomic_load(&fb[lane], __ATOMIC_RELAXED,
                                               __HIP_MEMORY_SCOPE_AGENT);
          if (__all(f == want)) break;
          __builtin_amdgcn_s_sleep(2);
        }
      }
      __syncthreads();  // detection complete
      const unsigned long long* sb = step + (size_t)(t - 1) * kH;
      unsigned long long v = __hip_atomic_load(&sb[tid], __ATOMIC_RELAXED,
                                               __HIP_MEMORY_SCOPE_AGENT);
      while ((unsigned)(v >> 32) != want) {  // near-never fallback
        __builtin_amdgcn_s_sleep(1);
        v = __hip_atomic_load(&sb[tid], __ATOMIC_RELAXED,
                              __HIP_MEMORY_SCOPE_AGENT);
      }
      hs[tid] = __uint_as_float((unsigned)v);
      __syncthreads();  // staging complete
#pragma unroll
      for (int u = 0; u < 16; ++u) hx[u] = hs[u * 64 + lane];
    }

    float ar = 0.f, az = 0.f, an = 0.f;
#pragma unroll
    for (int u = 0; u < 16; ++u) {
      ar += wr[u] * hx[u]; az += wz[u] * hx[u]; an += wn[u] * hx[u];
    }
    ar = warp_sum(ar); az = warp_sum(az); an = warp_sum(an);

    if (lane == 0) {
      const float gr = gis[0 * 1024 + w * kB + t];
      const float gz = gis[1 * 1024 + w * kB + t];
      const float gn = gis[2 * 1024 + w * kB + t];
      const float r = sigmoidf_(gr + ar + bhr);
      const float z = sigmoidf_(gz + az + bhz);
      const float xn = gn + r * (an + bhn);
      const float e2 = __expf(2.f * xn);
      const float n = 1.f - 2.f / (e2 + 1.f);   // tanh
      const float hn = (1.f - z) * n + z * cur;
      cur = hn;
      __hip_atomic_store(&step[(size_t)t * kH + j],
          (((unsigned long long)(t + 1)) << 32) | __float_as_uint(hn),
          __ATOMIC_RELAXED, __HIP_MEMORY_SCOPE_AGENT);
      rnn[(size_t)t * kH + j] = hn;
    }
    __syncthreads();  // every wave drains vmcnt before its barrier ->
                      // all 16 value stores retired before the flag
    if (tid == 0)
      __hip_atomic_store(&flg[(size_t)t * kB + bid], (unsigned)(t + 1),
                         __ATOMIC_RELAXED, __HIP_MEMORY_SCOPE_AGENT);
  }
}

// ---------------- w2h stage A: coalesced partials ----------------
// w2h[k] = sum_h v_attn[h]*W_attn[h][H+k]. grid 64 x 256.
__global__ __launch_bounds__(256) void k_w2hp(const float* __restrict__ W_attn,
    const float* __restrict__ v_attn, float* __restrict__ p2) {
  const int p = blockIdx.x, t = threadIdx.x;
  float ax = 0, ay = 0, az = 0, aw = 0;
#pragma unroll 4
  for (int hh = 0; hh < 16; ++hh) {
    const int h = p * 16 + hh;
    const float vh = v_attn[h];
    const float4 wq = *(const float4*)(W_attn + (size_t)h * 2048 + kH + 4 * t);
    ax += vh * wq.x; ay += vh * wq.y; az += vh * wq.z; aw += vh * wq.w;
  }
  *(float4*)(p2 + (size_t)p * kH + 4 * t) = make_float4(ax, ay, az, aw);
}

// ---------------- w2h stage B + hidden-output copy ---------------- grid 4x256
__global__ __launch_bounds__(256) void k_w2hr(const float* __restrict__ p2,
    const float* __restrict__ rnn, float* __restrict__ w2h,
    float* __restrict__ hid) {
  const int k = blockIdx.x * 256 + threadIdx.x;
  float a = 0.f;
#pragma unroll 8
  for (int p = 0; p < 64; ++p) a += p2[(size_t)p * kH + k];
  w2h[k] = a;
  hid[k] = rnn[63 * kH + k];
}

// ---------------- scores[b][s] = enc[s][b][:] . w2h ----------------
__global__ __launch_bounds__(256) void k_scores(const float* __restrict__ enc,
    const float* __restrict__ w2h, float* __restrict__ sc) {
  const int lane = threadIdx.x & 63;
  const int wg = blockIdx.x * 4 + (threadIdx.x >> 6);  // 0..16383
  const int b = wg & 63, s = wg >> 6;
  const float4* ep = (const float4*)(enc + ((size_t)s * kB + b) * kH) + lane * 4;
  const float4* wp = (const float4*)w2h + lane * 4;
  float acc = 0.f;
#pragma unroll
  for (int c = 0; c < 4; ++c) {
    const float4 e = ep[c], wq = wp[c];
    acc += e.x * wq.x + e.y * wq.y + e.z * wq.z + e.w * wq.w;
  }
  acc = warp_sum(acc);
  if (lane == 0) sc[b * kS + s] = acc;
}

// ---------------- softmax (fused) + context partials ----------------
// blockIdx = ch*64 + b; redundant row softmax then 64-s chunk accumulation.
__global__ __launch_bounds__(256) void k_context(const float* __restrict__ enc,
    const float* __restrict__ sc, float* __restrict__ attn,
    float* __restrict__ part) {
  __shared__ float sm[4], ss[4], ap[kS];
  const int b = blockIdx.x & 63, ch = blockIdx.x >> 6;
  const int t = threadIdx.x, lane = t & 63, w = t >> 6;
  const float x = sc[b * kS + t];
  float m = warp_max_all(x);
  if (lane == 0) sm[w] = m;
  __syncthreads();
  m = fmaxf(fmaxf(sm[0], sm[1]), fmaxf(sm[2], sm[3]));
  const float e = __expf(x - m);
  float s = warp_sum_all(e);
  if (lane == 0) ss[w] = s;
  __syncthreads();
  s = ss[0] + ss[1] + ss[2] + ss[3];
  const float p = e / s;
  ap[t] = p;
  if (ch == 0) attn[b * kS + t] = p;
  __syncthreads();
  const int h0_ = t * 4;
  float ax = 0, ay = 0, az = 0, aw = 0;
  const int s0 = ch * 64;
  for (int si = s0; si < s0 + 64; ++si) {
    const float a = ap[si];
    const float4 v = *(const float4*)(enc + ((size_t)si * kB + b) * kH + h0_);
    ax += a * v.x; ay += a * v.y; az += a * v.z; aw += a * v.w;
  }
  *(float4*)(part + ((size_t)ch * kB + b) * kH + h0_) =
      make_float4(ax, ay, az, aw);
}

// ---------------- coT[i][b] = tanh([rnn,ctx][b] . W_concat[i] + b_c[i]) ----------------
// One wave per (i, 8-b group); ctx formed inline from the 4 PART chunks.
__global__ __launch_bounds__(256) void k_concat(const float* __restrict__ rnn,
    const float* __restrict__ part, const float* __restrict__ W_c,
    const float* __restrict__ b_c, float* __restrict__ coT) {
  const int lane = threadIdx.x & 63;
  const int gw = blockIdx.x * 4 + (threadIdx.x >> 6);  // 0..8191
  const int i = gw >> 3, c = gw & 7;
  float wreg[32];
  {
    const float4* wp = (const float4*)(W_c + (size_t)i * 2048) + lane * 8;
#pragma unroll
    for (int cc = 0; cc < 8; ++cc) {
      const float4 f = wp[cc];
      wreg[cc * 4 + 0] = f.x; wreg[cc * 4 + 1] = f.y;
      wreg[cc * 4 + 2] = f.z; wreg[cc * 4 + 3] = f.w;
    }
  }
  const float bc = b_c[i];
  const int jcol = lane * 32;
  for (int bb = 0; bb < 8; ++bb) {
    const int b = c * 8 + bb;
    float acc = 0.f;
    if (jcol < kH) {
      const float* xr = rnn + (size_t)b * kH + jcol;
#pragma unroll
      for (int cc = 0; cc < 8; ++cc) {
        const float4 xv = *(const float4*)(xr + cc * 4);
        acc += wreg[cc * 4 + 0] * xv.x + wreg[cc * 4 + 1] * xv.y +
               wreg[cc * 4 + 2] * xv.z + wreg[cc * 4 + 3] * xv.w;
      }
    } else {
      const int hc = jcol - kH;
#pragma unroll
      for (int cc = 0; cc < 8; ++cc) {
        float4 xs = make_float4(0, 0, 0, 0);
#pragma unroll
        for (int ch = 0; ch < 4; ++ch) {
          const float4 pv = *(const float4*)(part +
              ((size_t)ch * kB + b) * kH + hc + cc * 4);
          xs.x += pv.x; xs.y += pv.y; xs.z += pv.z; xs.w += pv.w;
        }
        acc += wreg[cc * 4 + 0] * xs.x + wreg[cc * 4 + 1] * xs.y +
               wreg[cc * 4 + 2] * xs.z + wreg[cc * 4 + 3] * xs.w;
      }
    }
    acc = warp_sum(acc);
    if (lane == 0) coT[(size_t)i * kB + b] = tanhf(acc + bc);
  }
}

// ---------------- out[b][v] = coT[:,b] . W_out[v] + b_out[v] ----------------
// v5: exactly 250 blocks x 40 v-rows (10/wave) -- balanced (<=1 block/CU;
// r4's 313 blocks double-loaded 57 CUs). lane = b: coT reads coalesced;
// W_out rows wave-uniform (one line fetch per load, broadcast).
__global__ __launch_bounds__(256) void k_out(const float* __restrict__ coT,
    const float* __restrict__ W_out, const float* __restrict__ b_out,
    float* __restrict__ out) {
  const int b  = threadIdx.x & 63;
  const int vg = __builtin_amdgcn_readfirstlane(threadIdx.x >> 6);  // 0..3
  const int v0 = blockIdx.x * 40 + vg * 10;   // 250*40 = 10000 exactly
  float acc[10];
#pragma unroll
  for (int q = 0; q < 10; ++q) acc[q] = 0.f;
  for (int k0 = 0; k0 < kH; k0 += 4) {
    const float c0 = coT[(k0 + 0) * kB + b];
    const float c1 = coT[(k0 + 1) * kB + b];
    const float c2 = coT[(k0 + 2) * kB + b];
    const float c3 = coT[(k0 + 3) * kB + b];
#pragma unroll
    for (int q = 0; q < 10; ++q) {
      const float4 wq = *(const float4*)(W_out + (size_t)(v0 + q) * kH + k0);
      acc[q] += wq.x * c0 + wq.y * c1 + wq.z * c2 + wq.w * c3;
    }
  }
#pragma unroll
  for (int q = 0; q < 10; ++q)
    out[(size_t)b * kV + v0 + q] = acc[q] + b_out[v0 + q];
}

// ---------------- launcher ----------------
extern "C" void kernel_launch(void* const* d_in, const int* in_sizes, int n_in,
                              void* d_out, int out_size, void* d_ws,
                              size_t ws_size, hipStream_t stream) {
  const int*   seq    = (const int*)  d_in[0];
  const float* h0     = (const float*)d_in[1];
  const float* enc    = (const float*)d_in[2];
  const float* emb    = (const float*)d_in[3];
  const float* W_ih   = (const float*)d_in[4];
  const float* W_hh   = (const float*)d_in[5];
  const float* b_ih   = (const float*)d_in[6];
  const float* b_hh   = (const float*)d_in[7];
  const float* W_attn = (const float*)d_in[8];
  // d_in[9] = b_attn: drops out of softmax (shift invariance)
  const float* v_attn = (const float*)d_in[10];
  const float* W_conc = (const float*)d_in[11];
  const float* b_conc = (const float*)d_in[12];
  const float* W_outp = (const float*)d_in[13];
  const float* b_outp = (const float*)d_in[14];

  float* out      = (float*)d_out;           // (B,V) = 640000
  float* out_hid  = out + 640000;            // (1,1,H) = 1024
  float* out_attn = out + 641024;            // (B,1,S) = 16384

  float* ws = (float*)d_ws;
  float* GIp  = ws;                      // 3072*64 = 196608
  float* RNN  = ws + 196608;             // 64*1024 =  65536 -> 262144
  unsigned long long* STEP =
      (unsigned long long*)(ws + 262144);  // 64*1024 u64 = 131072 f -> 393216
  unsigned* FLG = (unsigned*)(ws + 393216); // 64*64 u32 = 4096 f -> 397312
  float* P2   = ws + 397312;             // 64*1024 =  65536 -> 462848
  float* W2H  = ws + 462848;             // 1024            -> 463872
  float* SC   = ws + 463872;             // 64*256  =  16384 -> 480256
  float* PART = ws + 480256;             // 4*64*1024=262144 -> 742400
  float* COT  = ws + 742400;             // 1024*64 =  65536 -> 807936 floats

  k_gi<<<768, 256, 0, stream>>>(seq, emb, W_ih, b_ih, GIp);
  k_gru<<<64, 1024, 0, stream>>>(h0, W_hh, b_hh, GIp, RNN, STEP, FLG);
  k_w2hp<<<64, 256, 0, stream>>>(W_attn, v_attn, P2);
  k_w2hr<<<4, 256, 0, stream>>>(P2, RNN, W2H, out_hid);
  k_scores<<<4096, 256, 0, stream>>>(enc, W2H, SC);
  k_context<<<256, 256, 0, stream>>>(enc, SC, out_attn, PART);
  k_concat<<<2048, 256, 0, stream>>>(RNN, PART, W_conc, b_conc, COT);
  k_out<<<250, 256, 0, stream>>>(COT, W_outp, b_outp, out);
}